// Round 2
// baseline (135.115 us; speedup 1.0000x reference)
//
#include <hip/hip_runtime.h>

// TensorTrain: out[b] = first(x0) . M0(x1) . ... . M29(x30) . last(x31)
// R=16, D=32, B=262144, bits in {0,1}.
// Meet-in-the-middle: V16[p=x0..x15] row-vector, W16[s=x16..x31] col-vector,
// out = V16[p] . W16[s]. Build: one LDS-staged kernel for byte tables,
// one kernel for 16-bit tables, one gather/dot kernel.

#define R 16
#define TT_D 32
#define BATCH 262144

// workspace layout, in floats (byte + 16-bit tables only)
#define OFF_V8   0                      // 256 x 16     x0..x7   row-vectors
#define OFF_P8   (OFF_V8 + 4096)        // 256 x 256    x8..x15  matrices (row-major 16x16)
#define OFF_Q8   (OFF_P8 + 65536)       // 256 x 256    x16..x23 matrices
#define OFF_W8   (OFF_Q8 + 65536)       // 256 x 16     x24..x31 col-vectors
#define OFF_V16  (OFF_W8 + 4096)        // 65536 x 16   prefix row-vectors
#define OFF_W16  (OFF_V16 + 1048576)    // 65536 x 16   suffix col-vectors
#define WS_FLOATS (OFF_W16 + 1048576)   // ~8.6 MB

typedef int   v4i __attribute__((ext_vector_type(4)));
typedef float v4f __attribute__((ext_vector_type(4)));
typedef float v2f __attribute__((ext_vector_type(2)));

// Row-chain product of 4 cores held in LDS, layout Lc[c][x][s][r] (r contiguous).
// v_out = row r of ( M[cbase](b0) . M[cbase+1](b1) . M[cbase+2](b2) . M[cbase+3](b3) )
__device__ inline void row_chain4(const float* __restrict__ Lc, int cbase, int e, int r,
                                  float* __restrict__ v) {
    const int b0 = (e >> 3) & 1, b1 = (e >> 2) & 1, b2 = (e >> 1) & 1, b3 = e & 1;
    #pragma unroll
    for (int s = 0; s < 16; s++) v[s] = Lc[((((cbase * 2 + b0) * 16) + s) << 4) + r];
    const int bits[3] = { b1, b2, b3 };
    #pragma unroll
    for (int k = 1; k <= 3; k++) {
        const float* M = Lc + (((cbase + k) * 2 + bits[k - 1]) << 8);
        float nv[16];
        #pragma unroll
        for (int s2 = 0; s2 < 16; s2++) {
            float acc = 0.f;
            #pragma unroll
            for (int r2 = 0; r2 < 16; r2++) acc += v[r2] * M[(s2 << 4) + r2];
            nv[s2] = acc;
        }
        #pragma unroll
        for (int s2 = 0; s2 < 16; s2++) v[s2] = nv[s2];
    }
}

// ---------------------------------------------------------------------------
// build1: 34 blocks.
//   g in [0,16): P8 rows for e8 in [g*16,(g+1)*16)   (cores 7..14)
//   g in [16,32): Q8 rows for e8 in [(g-16)*16, ...) (cores 15..22)
//   g == 32: V8 (first + cores 0..6)
//   g == 33: W8 (cores 23..29 + last)
// All core data staged in LDS transposed: Lc[c][x][s][r], r contiguous.
__global__ __launch_bounds__(256) void tt_build1(const float* __restrict__ cf,
                                                 const float* __restrict__ cm,
                                                 const float* __restrict__ cl,
                                                 float* __restrict__ ws) {
    __shared__ float sh[12288];          // 48 KB: [0,4096) Lc, [4096,8192) H/A/F, [8192,..) L / vecs
    const int g = blockIdx.x;
    const int t = threadIdx.x;

    if (g < 32) {
        const bool isP = (g < 16);
        const int gb = isP ? g : g - 16;
        const int coreBase = isP ? 7 : 15;          // 8 cores staged
        // stage cores coreBase..coreBase+7: global addr is i + coreBase*512 (coalesced)
        for (int i = t; i < 8 * 512; i += 256) {
            const int c = i >> 9, j = i & 511;
            const int x = j & 1, s = (j >> 1) & 15, r = j >> 5;
            sh[(((c * 2 + x) * 16) + s) * 16 + r] = cm[coreBase * 512 + i];
        }
        __syncthreads();
        // L nibble table (cores local 4..7): 256 tasks
        {
            const int e = t >> 4, r = t & 15;
            float v[16];
            row_chain4(sh, 4, e, r, v);
            #pragma unroll
            for (int s = 0; s < 16; s++) sh[8192 + (e << 8) + (r << 4) + s] = v[s];
        }
        // H nibble: only entry gb needed: 16 row tasks on t<16
        if (t < 16) {
            float v[16];
            row_chain4(sh, 0, gb, t, v);
            #pragma unroll
            for (int s = 0; s < 16; s++) sh[4096 + (t << 4) + s] = v[s];
        }
        __syncthreads();
        // byte matrix rows: thread t = (l<<4)|r -> row r of H[gb] @ L[l]
        {
            const int l = t >> 4, r = t & 15;
            float h[16], outv[16];
            #pragma unroll
            for (int k = 0; k < 16; k++) h[k] = sh[4096 + (r << 4) + k];
            #pragma unroll
            for (int s2 = 0; s2 < 16; s2++) outv[s2] = 0.f;
            #pragma unroll
            for (int k = 0; k < 16; k++) {
                const float a = h[k];
                #pragma unroll
                for (int s2 = 0; s2 < 16; s2++) outv[s2] += a * sh[8192 + (l << 8) + (k << 4) + s2];
            }
            const int e8 = gb * 16 + l;
            float* o = ws + (isP ? OFF_P8 : OFF_Q8) + (e8 << 8) + (r << 4);
            #pragma unroll
            for (int s2 = 0; s2 < 16; s2++) o[s2] = outv[s2];
        }
    } else if (g == 32) {
        // stage cores 0..6 + cf
        for (int i = t; i < 7 * 512; i += 256) {
            const int c = i >> 9, j = i & 511;
            const int x = j & 1, s = (j >> 1) & 15, r = j >> 5;
            sh[(((c * 2 + x) * 16) + s) * 16 + r] = cm[i];
        }
        if (t < 32) sh[8192 + t] = cf[t];
        __syncthreads();
        // A table (cores 3..6): 256 tasks
        {
            const int e = t >> 4, r = t & 15;
            float v[16];
            row_chain4(sh, 3, e, r, v);
            #pragma unroll
            for (int s = 0; s < 16; s++) sh[4096 + (e << 8) + (r << 4) + s] = v[s];
        }
        // V4 vectors (first . M0 . M1 . M2): t<16
        if (t < 16) {
            const int e = t;
            const int b0 = (e >> 3) & 1, b1 = (e >> 2) & 1, b2 = (e >> 1) & 1, b3 = e & 1;
            float v[16];
            #pragma unroll
            for (int s = 0; s < 16; s++) v[s] = sh[8192 + s * 2 + b0];
            const int bits[3] = { b1, b2, b3 };
            #pragma unroll
            for (int k = 1; k <= 3; k++) {
                const float* M = sh + (((k - 1) * 2 + bits[k - 1]) << 8);
                float nv[16];
                #pragma unroll
                for (int s2 = 0; s2 < 16; s2++) {
                    float acc = 0.f;
                    #pragma unroll
                    for (int r2 = 0; r2 < 16; r2++) acc += v[r2] * M[(s2 << 4) + r2];
                    nv[s2] = acc;
                }
                #pragma unroll
                for (int s2 = 0; s2 < 16; s2++) v[s2] = nv[s2];
            }
            #pragma unroll
            for (int s = 0; s < 16; s++) sh[8256 + (e << 4) + s] = v[s];
        }
        __syncthreads();
        // V8[e8] = V4[h] . A[l]; thread t = e8
        {
            const int h = t >> 4, l = t & 15;
            float outv[16];
            #pragma unroll
            for (int s2 = 0; s2 < 16; s2++) outv[s2] = 0.f;
            #pragma unroll
            for (int k = 0; k < 16; k++) {
                const float a = sh[8256 + (h << 4) + k];
                #pragma unroll
                for (int s2 = 0; s2 < 16; s2++) outv[s2] += a * sh[4096 + (l << 8) + (k << 4) + s2];
            }
            float* o = ws + OFF_V8 + (t << 4);
            #pragma unroll
            for (int s2 = 0; s2 < 16; s2++) o[s2] = outv[s2];
        }
    } else {
        // g == 33: stage cores 23..29 + cl
        for (int i = t; i < 7 * 512; i += 256) {
            const int c = i >> 9, j = i & 511;
            const int x = j & 1, s = (j >> 1) & 15, r = j >> 5;
            sh[(((c * 2 + x) * 16) + s) * 16 + r] = cm[23 * 512 + i];
        }
        if (t < 32) sh[8192 + t] = cl[t];
        __syncthreads();
        // F table (cores 23..26 = local 0..3): 256 tasks
        {
            const int e = t >> 4, r = t & 15;
            float v[16];
            row_chain4(sh, 0, e, r, v);
            #pragma unroll
            for (int s = 0; s < 16; s++) sh[4096 + (e << 8) + (r << 4) + s] = v[s];
        }
        // W4 col-vectors (M27.M28.M29.last): t<16; local cores 4,5,6 = 27,28,29
        if (t < 16) {
            const int e = t;
            const int b0 = (e >> 3) & 1, b1 = (e >> 2) & 1, b2 = (e >> 1) & 1, b3 = e & 1;
            float w[16];
            #pragma unroll
            for (int r2 = 0; r2 < 16; r2++) w[r2] = sh[8192 + r2 * 2 + b3];
            const int cidx[3] = { 6, 5, 4 };
            const int bidx[3] = { b2, b1, b0 };
            #pragma unroll
            for (int k = 0; k < 3; k++) {
                const float* M = sh + ((cidx[k] * 2 + bidx[k]) << 8);   // M[r][kk] at M[(kk<<4)+r]
                float nw[16];
                #pragma unroll
                for (int r2 = 0; r2 < 16; r2++) {
                    float acc = 0.f;
                    #pragma unroll
                    for (int kk = 0; kk < 16; kk++) acc += M[(kk << 4) + r2] * w[kk];
                    nw[r2] = acc;
                }
                #pragma unroll
                for (int r2 = 0; r2 < 16; r2++) w[r2] = nw[r2];
            }
            #pragma unroll
            for (int r2 = 0; r2 < 16; r2++) sh[8256 + (e << 4) + r2] = w[r2];
        }
        __syncthreads();
        // W8[e8] = F[h] @ W4[l]; thread t = e8
        {
            const int h = t >> 4, l = t & 15;
            float w4[16], outv[16];
            #pragma unroll
            for (int k = 0; k < 16; k++) w4[k] = sh[8256 + (l << 4) + k];
            #pragma unroll
            for (int r2 = 0; r2 < 16; r2++) {
                float acc = 0.f;
                #pragma unroll
                for (int k = 0; k < 16; k++) acc += sh[4096 + (h << 8) + (r2 << 4) + k] * w4[k];
                outv[r2] = acc;
            }
            float* o = ws + OFF_W8 + (t << 4);
            #pragma unroll
            for (int r2 = 0; r2 < 16; r2++) o[r2] = outv[r2];
        }
    }
}

// ---------------------------------------------------------------------------
// build2: 16-bit tables. blocks 0..255: V16 (h = block, l = thread);
// blocks 256..511: W16.
__global__ __launch_bounds__(256) void tt_build2(float* __restrict__ ws) {
    const int t = threadIdx.x;
    if (blockIdx.x < 256) {
        const int h = blockIdx.x, l = t;
        __shared__ float sv[16];
        if (t < 16) sv[t] = ws[OFF_V8 + h * 16 + t];
        __syncthreads();
        const float* P = ws + OFF_P8 + (l << 8);
        float outv[16];
        #pragma unroll
        for (int s2 = 0; s2 < 16; s2++) outv[s2] = 0.f;
        #pragma unroll
        for (int r2 = 0; r2 < 16; r2++) {
            const float a = sv[r2];
            #pragma unroll
            for (int s2 = 0; s2 < 16; s2++) outv[s2] += a * P[(r2 << 4) + s2];
        }
        float* o = ws + OFF_V16 + (size_t)((h << 8) + l) * 16;
        #pragma unroll
        for (int s2 = 0; s2 < 16; s2++) o[s2] = outv[s2];
    } else {
        const int h = blockIdx.x - 256, l = t;
        __shared__ float sQ[256];
        sQ[t] = ws[OFF_Q8 + (h << 8) + t];
        __syncthreads();
        const float* wv = ws + OFF_W8 + (l << 4);
        float w[16];
        #pragma unroll
        for (int k = 0; k < 16; k++) w[k] = wv[k];
        float outv[16];
        #pragma unroll
        for (int r2 = 0; r2 < 16; r2++) {
            float acc = 0.f;
            #pragma unroll
            for (int k = 0; k < 16; k++) acc += sQ[(r2 << 4) + k] * w[k];
            outv[r2] = acc;
        }
        float* o = ws + OFF_W16 + (size_t)((h << 8) + l) * 16;
        #pragma unroll
        for (int r2 = 0; r2 < 16; r2++) o[r2] = outv[r2];
    }
}

// ---------------------------------------------------------------------------
// main: 2 batch elements per thread. Nontemporal X stream (don't evict the
// 8 MB tables from L2); cached table gathers; nontemporal out store.
__global__ __launch_bounds__(256) void tt_main2(const int* __restrict__ X,
                                                const float* __restrict__ ws,
                                                float* __restrict__ out) {
    const int tid = blockIdx.x * 256 + threadIdx.x;     // handles b = 2*tid, 2*tid+1
    const v4i* Xr = (const v4i*)(X + (size_t)tid * 64);
    v4i c[16];
    #pragma unroll
    for (int q = 0; q < 16; q++) c[q] = __builtin_nontemporal_load(Xr + q);

    unsigned key[4] = { 0u, 0u, 0u, 0u };               // p0, s0, p1, s1
    #pragma unroll
    for (int q = 0; q < 16; q++) {
        const unsigned nib = ((unsigned)(c[q].x & 1) << 3) | ((unsigned)(c[q].y & 1) << 2) |
                             ((unsigned)(c[q].z & 1) << 1) | (unsigned)(c[q].w & 1);
        key[q >> 2] = (key[q >> 2] << 4) | nib;
    }

    const v4f* v0 = (const v4f*)(ws + OFF_V16 + (size_t)key[0] * 16);
    const v4f* w0 = (const v4f*)(ws + OFF_W16 + (size_t)key[1] * 16);
    const v4f* v1 = (const v4f*)(ws + OFF_V16 + (size_t)key[2] * 16);
    const v4f* w1 = (const v4f*)(ws + OFF_W16 + (size_t)key[3] * 16);

    v4f acc0 = { 0.f, 0.f, 0.f, 0.f }, acc1 = { 0.f, 0.f, 0.f, 0.f };
    #pragma unroll
    for (int k = 0; k < 4; k++) acc0 += v0[k] * w0[k];
    #pragma unroll
    for (int k = 0; k < 4; k++) acc1 += v1[k] * w1[k];

    v2f res;
    res.x = acc0.x + acc0.y + acc0.z + acc0.w;
    res.y = acc1.x + acc1.y + acc1.z + acc1.w;
    __builtin_nontemporal_store(res, (v2f*)(out + (size_t)tid * 2));
}

// ---------------------------------------------------------------------------
// Fallback: direct per-thread chain (only if ws too small).
__global__ __launch_bounds__(256) void tt_direct(const int* __restrict__ X,
                                                 const float* __restrict__ cf,
                                                 const float* __restrict__ cm,
                                                 const float* __restrict__ cl,
                                                 float* __restrict__ out) {
    __shared__ float scm[30 * 16 * 16 * 2];
    for (int i = threadIdx.x; i < 30 * 16 * 16 * 2; i += blockDim.x) scm[i] = cm[i];
    __syncthreads();
    const int b = blockIdx.x * blockDim.x + threadIdx.x;
    if (b >= BATCH) return;
    const int* xr = X + (size_t)b * TT_D;
    float v[R], nv[R];
    const int x0 = xr[0] & 1;
    #pragma unroll
    for (int r = 0; r < R; r++) v[r] = cf[r * 2 + x0];
    for (int i = 1; i <= 30; i++) {
        const int bit = xr[i] & 1;
        const float* M = scm + (i - 1) * 512;
        #pragma unroll
        for (int s2 = 0; s2 < R; s2++) {
            float acc = 0.f;
            #pragma unroll
            for (int r = 0; r < R; r++) acc += v[r] * M[(r * 16 + s2) * 2 + bit];
            nv[s2] = acc;
        }
        #pragma unroll
        for (int s2 = 0; s2 < R; s2++) v[s2] = nv[s2];
    }
    const int xl = xr[31] & 1;
    float acc = 0.f;
    #pragma unroll
    for (int r = 0; r < R; r++) acc += v[r] * cl[r * 2 + xl];
    out[b] = acc;
}

extern "C" void kernel_launch(void* const* d_in, const int* in_sizes, int n_in,
                              void* d_out, int out_size, void* d_ws, size_t ws_size,
                              hipStream_t stream) {
    const int* X = (const int*)d_in[0];
    const float* cf = (const float*)d_in[1];
    const float* cm = (const float*)d_in[2];
    const float* cl = (const float*)d_in[3];
    float* out = (float*)d_out;

    if (ws_size >= (size_t)WS_FLOATS * sizeof(float)) {
        float* ws = (float*)d_ws;
        tt_build1<<<34, 256, 0, stream>>>(cf, cm, cl, ws);
        tt_build2<<<512, 256, 0, stream>>>(ws);
        tt_main2<<<BATCH / 512, 256, 0, stream>>>(X, ws, out);
    } else {
        tt_direct<<<(BATCH + 255) / 256, 256, 0, stream>>>(X, cf, cm, cl, out);
    }
}

// Round 3
// 129.177 us; speedup vs baseline: 1.0460x; 1.0460x over previous
//
#include <hip/hip_runtime.h>

// TensorTrain: out[b] = first(x0) . M0(x1) . ... . M29(x30) . last(x31)
// R=16, D=32, B=262144, bits in {0,1}.
// Meet-in-the-middle: V16[p=x0..x15] row-vector, W16[s=x16..x31] col-vector,
// out = V16[p] . W16[s].
// Build is wide-and-shallow: one block per byte-table entry, LDS ping-pong
// matmul chain (small code, high TLP) — the R2 build1 (34 blocks, giant
// unrolled serial chains) was latency-serialization-bound at 56 us.

#define R 16
#define TT_D 32
#define BATCH 262144

// workspace layout, in floats
#define OFF_V8   0                      // 256 x 16     first + cores 0..6   (x0..x7)  row-vectors
#define OFF_P8   (OFF_V8 + 4096)        // 256 x 256    cores 7..14          (x8..x15) 16x16 row-major
#define OFF_Q8   (OFF_P8 + 65536)       // 256 x 256    cores 15..22         (x16..x23)
#define OFF_W8   (OFF_Q8 + 65536)       // 256 x 16     cores 23..29 + last  (x24..x31) col-vectors
#define OFF_V16  (OFF_W8 + 4096)        // 65536 x 16   prefix row-vectors
#define OFF_W16  (OFF_V16 + 1048576)    // 65536 x 16   suffix col-vectors
#define WS_FLOATS (OFF_W16 + 1048576)   // ~8.6 MB

typedef int   v4i __attribute__((ext_vector_type(4)));
typedef float v4f __attribute__((ext_vector_type(4)));
typedef float v2f __attribute__((ext_vector_type(2)));

// ---------------------------------------------------------------------------
// Byte tables. 544 blocks:
//   g in [0,256):    P8 entry e=g   : product of cores 7..14,  bit j from e>>(7-j)
//   g in [256,512):  Q8 entry e=g-256: product of cores 15..22
//   g in [512,528):  V8, 16 entries per block (first + cores 0..6)
//   g in [528,544):  W8, 16 entries per block (cores 23..29 + last)
// Matrix blocks: thread t=(r<<4)|s computes C[r][s]; chain via LDS ping-pong,
// one barrier per step. Cores read directly from global (L2-hot, 60 KB total).
__global__ __launch_bounds__(256) void tt_byte_build(const float* __restrict__ cf,
                                                     const float* __restrict__ cm,
                                                     const float* __restrict__ cl,
                                                     float* __restrict__ ws) {
    __shared__ float sA[256], sB[256];
    const int g = blockIdx.x;
    const int t = threadIdx.x;

    if (g < 512) {
        const bool isP = (g < 256);
        const int e = g & 255;
        const int base = isP ? 7 : 15;
        const int r = t >> 4, s = t & 15;
        // init: C = M_base(bit7 of e)
        {
            const int b = (e >> 7) & 1;
            sA[t] = cm[(((base * 16 + r) * 16) + s) * 2 + b];
        }
        float* cur = sA; float* nxt = sB;
        float acc = 0.f;
        for (int j = 1; j < 8; j++) {
            __syncthreads();
            const int b = (e >> (7 - j)) & 1;
            const float* M = cm + (base + j) * 512 + b;   // element (k,s) at M[(k*16+s)*2]
            acc = 0.f;
            #pragma unroll
            for (int k = 0; k < 16; k++)
                acc += cur[r * 16 + k] * M[(k * 16 + s) * 2];
            nxt[t] = acc;
            float* tmp = cur; cur = nxt; nxt = tmp;
        }
        // cur[t] is this thread's own last write
        ws[(isP ? OFF_P8 : OFF_Q8) + (e << 8) + t] = acc;
    } else if (g < 528) {
        // V8: 16 entries e = eb + el; thread t = (el<<4)|s
        const int eb = (g - 512) * 16;
        const int el = t >> 4, s = t & 15;
        const int e = eb + el;
        sA[t] = cf[s * 2 + ((e >> 7) & 1)];
        float* cur = sA; float* nxt = sB;
        float acc = 0.f;
        for (int j = 0; j < 7; j++) {
            __syncthreads();
            const int b = (e >> (6 - j)) & 1;
            const float* M = cm + j * 512 + b;            // element (r2,s) at M[(r2*16+s)*2]
            acc = 0.f;
            #pragma unroll
            for (int r2 = 0; r2 < 16; r2++)
                acc += cur[el * 16 + r2] * M[(r2 * 16 + s) * 2];
            nxt[t] = acc;
            float* tmp = cur; cur = nxt; nxt = tmp;
        }
        ws[OFF_V8 + eb * 16 + t] = acc;                   // = (e<<4)+s, coalesced
    } else {
        // W8: 16 entries; thread t = (el<<4)|r, col-vector chain from the back
        const int eb = (g - 528) * 16;
        const int el = t >> 4, r = t & 15;
        const int e = eb + el;
        sA[t] = cl[r * 2 + (e & 1)];
        float* cur = sA; float* nxt = sB;
        float acc = 0.f;
        for (int j = 0; j < 7; j++) {
            __syncthreads();
            const int c = 29 - j;
            const int b = (e >> (1 + j)) & 1;
            const float* M = cm + c * 512 + b;            // element (r,k) at M[(r*16+k)*2]
            acc = 0.f;
            #pragma unroll
            for (int k = 0; k < 16; k++)
                acc += M[(r * 16 + k) * 2] * cur[el * 16 + k];
            nxt[t] = acc;
            float* tmp = cur; cur = nxt; nxt = tmp;
        }
        ws[OFF_W8 + eb * 16 + t] = acc;
    }
}

// ---------------------------------------------------------------------------
// 16-bit tables. 512 blocks.
//   blocks 0..255 (V16): block = LO byte l. Stage P8[l] (1 KB) in LDS
//     (broadcast reads); thread h reads V8[h] coalesced; writes scattered
//     full 64 B lines.
//   blocks 256..511 (W16): block = HI byte h. Stage Q8[h] in LDS; thread l
//     reads W8[l] coalesced; writes perfectly contiguous 16 KB.
__global__ __launch_bounds__(256) void tt_tab(float* __restrict__ ws) {
    const int t = threadIdx.x;
    if (blockIdx.x < 256) {
        const int l = blockIdx.x;
        __shared__ float sP[256];
        sP[t] = ws[OFF_P8 + (l << 8) + t];
        __syncthreads();
        const int h = t;
        const float* v8 = ws + OFF_V8 + (h << 4);
        float v[16];
        #pragma unroll
        for (int k = 0; k < 16; k++) v[k] = v8[k];
        float o[16];
        #pragma unroll
        for (int s = 0; s < 16; s++) o[s] = 0.f;
        #pragma unroll
        for (int r = 0; r < 16; r++) {
            const float a = v[r];
            #pragma unroll
            for (int s = 0; s < 16; s++) o[s] += a * sP[r * 16 + s];
        }
        float* dst = ws + OFF_V16 + ((size_t)((h << 8) | l) << 4);
        #pragma unroll
        for (int s = 0; s < 16; s++) dst[s] = o[s];
    } else {
        const int h = blockIdx.x - 256;
        __shared__ float sQ[256];
        sQ[t] = ws[OFF_Q8 + (h << 8) + t];
        __syncthreads();
        const int l = t;
        const float* w8 = ws + OFF_W8 + (l << 4);
        float w[16];
        #pragma unroll
        for (int k = 0; k < 16; k++) w[k] = w8[k];
        float o[16];
        #pragma unroll
        for (int r = 0; r < 16; r++) {
            float acc = 0.f;
            #pragma unroll
            for (int k = 0; k < 16; k++) acc += sQ[r * 16 + k] * w[k];
            o[r] = acc;
        }
        float* dst = ws + OFF_W16 + ((size_t)((h << 8) | l) << 4);
        #pragma unroll
        for (int r = 0; r < 16; r++) dst[r] = o[r];
    }
}

// ---------------------------------------------------------------------------
// main: 2 batch elements per thread. Nontemporal X stream (don't evict the
// 8 MB tables from L2); cached table gathers; nontemporal out store.
__global__ __launch_bounds__(256) void tt_main2(const int* __restrict__ X,
                                                const float* __restrict__ ws,
                                                float* __restrict__ out) {
    const int tid = blockIdx.x * 256 + threadIdx.x;     // handles b = 2*tid, 2*tid+1
    const v4i* Xr = (const v4i*)(X + (size_t)tid * 64);
    v4i c[16];
    #pragma unroll
    for (int q = 0; q < 16; q++) c[q] = __builtin_nontemporal_load(Xr + q);

    unsigned key[4] = { 0u, 0u, 0u, 0u };               // p0, s0, p1, s1
    #pragma unroll
    for (int q = 0; q < 16; q++) {
        const unsigned nib = ((unsigned)(c[q].x & 1) << 3) | ((unsigned)(c[q].y & 1) << 2) |
                             ((unsigned)(c[q].z & 1) << 1) | (unsigned)(c[q].w & 1);
        key[q >> 2] = (key[q >> 2] << 4) | nib;
    }

    const v4f* v0 = (const v4f*)(ws + OFF_V16 + (size_t)key[0] * 16);
    const v4f* w0 = (const v4f*)(ws + OFF_W16 + (size_t)key[1] * 16);
    const v4f* v1 = (const v4f*)(ws + OFF_V16 + (size_t)key[2] * 16);
    const v4f* w1 = (const v4f*)(ws + OFF_W16 + (size_t)key[3] * 16);

    v4f acc0 = { 0.f, 0.f, 0.f, 0.f }, acc1 = { 0.f, 0.f, 0.f, 0.f };
    #pragma unroll
    for (int k = 0; k < 4; k++) acc0 += v0[k] * w0[k];
    #pragma unroll
    for (int k = 0; k < 4; k++) acc1 += v1[k] * w1[k];

    v2f res;
    res.x = acc0.x + acc0.y + acc0.z + acc0.w;
    res.y = acc1.x + acc1.y + acc1.z + acc1.w;
    __builtin_nontemporal_store(res, (v2f*)(out + (size_t)tid * 2));
}

// ---------------------------------------------------------------------------
// Fallback: direct per-thread chain (only if ws too small).
__global__ __launch_bounds__(256) void tt_direct(const int* __restrict__ X,
                                                 const float* __restrict__ cf,
                                                 const float* __restrict__ cm,
                                                 const float* __restrict__ cl,
                                                 float* __restrict__ out) {
    __shared__ float scm[30 * 16 * 16 * 2];
    for (int i = threadIdx.x; i < 30 * 16 * 16 * 2; i += blockDim.x) scm[i] = cm[i];
    __syncthreads();
    const int b = blockIdx.x * blockDim.x + threadIdx.x;
    if (b >= BATCH) return;
    const int* xr = X + (size_t)b * TT_D;
    float v[R], nv[R];
    const int x0 = xr[0] & 1;
    #pragma unroll
    for (int r = 0; r < R; r++) v[r] = cf[r * 2 + x0];
    for (int i = 1; i <= 30; i++) {
        const int bit = xr[i] & 1;
        const float* M = scm + (i - 1) * 512;
        #pragma unroll
        for (int s2 = 0; s2 < R; s2++) {
            float acc = 0.f;
            #pragma unroll
            for (int r = 0; r < R; r++) acc += v[r] * M[(r * 16 + s2) * 2 + bit];
            nv[s2] = acc;
        }
        #pragma unroll
        for (int s2 = 0; s2 < R; s2++) v[s2] = nv[s2];
    }
    const int xl = xr[31] & 1;
    float acc = 0.f;
    #pragma unroll
    for (int r = 0; r < R; r++) acc += v[r] * cl[r * 2 + xl];
    out[b] = acc;
}

extern "C" void kernel_launch(void* const* d_in, const int* in_sizes, int n_in,
                              void* d_out, int out_size, void* d_ws, size_t ws_size,
                              hipStream_t stream) {
    const int* X = (const int*)d_in[0];
    const float* cf = (const float*)d_in[1];
    const float* cm = (const float*)d_in[2];
    const float* cl = (const float*)d_in[3];
    float* out = (float*)d_out;

    if (ws_size >= (size_t)WS_FLOATS * sizeof(float)) {
        float* ws = (float*)d_ws;
        tt_byte_build<<<544, 256, 0, stream>>>(cf, cm, cl, ws);
        tt_tab<<<512, 256, 0, stream>>>(ws);
        tt_main2<<<BATCH / 512, 256, 0, stream>>>(X, ws, out);
    } else {
        tt_direct<<<(BATCH + 255) / 256, 256, 0, stream>>>(X, cf, cm, cl, out);
    }
}